// Round 1
// baseline (1466.444 us; speedup 1.0000x reference)
//
#include <hip/hip_runtime.h>

// Problem constants (match reference)
#define N_NODES 10000
#define N_EDGES 160000
#define DIM_IN 32
#define DIM_OUT 64
#define DIM_HID 128
#define BOND 13
#define NB 4  // source nodes per workgroup in main kernel

static __device__ __forceinline__ unsigned short f2bf(float f) {
    union { float f; unsigned u; } c; c.f = f;
    unsigned r = c.u + 0x7FFF + ((c.u >> 16) & 1);  // RNE
    return (unsigned short)(r >> 16);
}
static __device__ __forceinline__ float bf2f(unsigned short b) {
    union { unsigned u; float f; } c; c.u = ((unsigned)b) << 16;
    return c.f;
}

// ---- CSR build: histogram of src ----
__global__ void hist_kernel(const int* __restrict__ ei, int* __restrict__ counts) {
    int e = blockIdx.x * 256 + threadIdx.x;
    if (e < N_EDGES) atomicAdd(&counts[ei[e]], 1);
}

// ---- single-block exclusive scan in place (counts -> offsets) ----
__global__ void scan_kernel(int* __restrict__ counts) {
    __shared__ int s[1024];
    const int t = threadIdx.x;
    const int base = t * 10;  // 1024*10 >= 10000
    int loc[10];
    int sum = 0;
#pragma unroll
    for (int u = 0; u < 10; ++u) {
        int idx = base + u;
        int v = (idx < N_NODES) ? counts[idx] : 0;
        loc[u] = v; sum += v;
    }
    s[t] = sum;
    __syncthreads();
    for (int off = 1; off < 1024; off <<= 1) {
        int add = (t >= off) ? s[t - off] : 0;
        __syncthreads();
        s[t] += add;
        __syncthreads();
    }
    int run = s[t] - sum;  // exclusive prefix of this thread's segment
#pragma unroll
    for (int u = 0; u < 10; ++u) {
        int idx = base + u;
        if (idx < N_NODES) counts[idx] = run;
        run += loc[u];
    }
}

__global__ void copycur_kernel(const int* __restrict__ off, int* __restrict__ cur) {
    int i = blockIdx.x * 256 + threadIdx.x;
    if (i < N_NODES) cur[i] = off[i];
}

// ---- scatter edge ids into CSR order (cursor ends up = offsets[n+1]) ----
__global__ void scatter_kernel(const int* __restrict__ ei, int* __restrict__ cur,
                               int* __restrict__ es) {
    int e = blockIdx.x * 256 + threadIdx.x;
    if (e < N_EDGES) {
        int pos = atomicAdd(&cur[ei[e]], 1);
        es[pos] = e;
    }
}

// ---- main: per source-node P = x·W2 (in LDS, bf16), then per-edge msg = h·P ----
__global__ __launch_bounds__(256) void main_kernel(
    const float* __restrict__ x, const int* __restrict__ ei,
    const float* __restrict__ ea, const float* __restrict__ W1,
    const float* __restrict__ b1, const float* __restrict__ W2,
    const float* __restrict__ b2, const int* __restrict__ offsets,
    const int* __restrict__ cursor, const int* __restrict__ es,
    float* __restrict__ agg)
{
    __shared__ unsigned short Pb[NB][DIM_HID][DIM_OUT];  // 64 KiB bf16
    __shared__ float xs[NB][DIM_IN];
    __shared__ float Qs[NB][DIM_OUT];
    __shared__ float hs[DIM_HID];
    __shared__ float red[4][DIM_OUT];

    const int t  = threadIdx.x;
    const int o  = t & 63;    // output column
    const int kg = t >> 6;    // k-group 0..3 (one wave per group)
    const int n0 = blockIdx.x * NB;

    if (t < NB * DIM_IN) {
        int j = t >> 5, i = t & 31;
        xs[j][i] = x[(n0 + j) * DIM_IN + i];
    }
    __syncthreads();

    // P[n,k,o] = sum_i x[n,i] * W2[k, i*64+o]; W2 reads coalesced (o contiguous),
    // amortized over NB nodes per load.
    for (int kk = 0; kk < DIM_HID / 4; ++kk) {
        const int k = kg * (DIM_HID / 4) + kk;
        const float* w2p = W2 + k * (DIM_IN * DIM_OUT) + o;
        float a0 = 0.f, a1 = 0.f, a2 = 0.f, a3 = 0.f;
#pragma unroll
        for (int i = 0; i < DIM_IN; ++i) {
            float w = w2p[i * DIM_OUT];
            a0 += xs[0][i] * w; a1 += xs[1][i] * w;
            a2 += xs[2][i] * w; a3 += xs[3][i] * w;
        }
        Pb[0][k][o] = f2bf(a0); Pb[1][k][o] = f2bf(a1);
        Pb[2][k][o] = f2bf(a2); Pb[3][k][o] = f2bf(a3);
    }
    // Q[n,o] = sum_i x[n,i]*b2[i*64+o]  (b2 is zeros in setup, kept for correctness)
    {
        float q = 0.f;
#pragma unroll
        for (int i = 0; i < DIM_IN; ++i) q += xs[kg][i] * b2[i * DIM_OUT + o];
        Qs[kg][o] = q;
    }
    __syncthreads();

    for (int j = 0; j < NB; ++j) {
        const int n = n0 + j;
        const int start = offsets[n];
        const int end   = cursor[n];  // == offsets[n+1] after scatter
        for (int p = start; p < end; ++p) {
            const int e = es[p];
            // edge MLP hidden: h = relu(ea@W1 + b1), 128 threads
            if (t < DIM_HID) {
                float a = b1[t];
                const float* eap = ea + e * BOND;
#pragma unroll
                for (int jj = 0; jj < BOND; ++jj) a += eap[jj] * W1[jj * DIM_HID + t];
                hs[t] = a > 0.f ? a : 0.f;
            }
            __syncthreads();
            // msg[o] = sum_k h[k] * P[j][k][o]; each wave handles 32 k's
            float part = 0.f;
#pragma unroll
            for (int kk = 0; kk < DIM_HID / 4; ++kk) {
                int k = kg * (DIM_HID / 4) + kk;
                part += hs[k] * bf2f(Pb[j][k][o]);
            }
            red[kg][o] = part;
            __syncthreads();
            if (t < DIM_OUT) {
                float m = red[0][t] + red[1][t] + red[2][t] + red[3][t] + Qs[j][t];
                atomicAdd(&agg[ei[N_EDGES + e] * DIM_OUT + t], m);
            }
            __syncthreads();
        }
    }
}

// ---- finalize: out = relu(agg + x@root + bias), in place on d_out ----
__global__ void finalize_kernel(const float* __restrict__ x,
                                const float* __restrict__ root,
                                const float* __restrict__ bias,
                                float* __restrict__ out) {
    int idx = blockIdx.x * 256 + threadIdx.x;
    if (idx >= N_NODES * DIM_OUT) return;
    int n = idx >> 6, o = idx & 63;
    float r = bias[o];
    const float* xn = x + n * DIM_IN;
#pragma unroll
    for (int i = 0; i < DIM_IN; ++i) r += xn[i] * root[i * DIM_OUT + o];
    float v = out[idx] + r;
    out[idx] = v > 0.f ? v : 0.f;
}

extern "C" void kernel_launch(void* const* d_in, const int* in_sizes, int n_in,
                              void* d_out, int out_size, void* d_ws, size_t ws_size,
                              hipStream_t stream) {
    const float* x    = (const float*)d_in[0];
    const int*   ei   = (const int*)d_in[1];   // [2, E]: row 0 = src, row 1 = dst
    const float* ea   = (const float*)d_in[2];
    const float* W1   = (const float*)d_in[3];
    const float* b1   = (const float*)d_in[4];
    const float* W2   = (const float*)d_in[5];
    const float* b2   = (const float*)d_in[6];
    const float* root = (const float*)d_in[7];
    const float* bias = (const float*)d_in[8];
    float* out = (float*)d_out;

    // Workspace layout (720 KB total; ws re-poisoned each call so we rebuild all)
    char* ws = (char*)d_ws;
    int* counts = (int*)(ws);           // 40000 B  (becomes exclusive offsets)
    int* cursor = (int*)(ws + 40064);   // 40000 B  (becomes offsets[n+1])
    int* es     = (int*)(ws + 80128);   // 640000 B (edge ids sorted by src)

    hipMemsetAsync(d_out, 0, (size_t)N_NODES * DIM_OUT * sizeof(float), stream);
    hipMemsetAsync(counts, 0, N_NODES * sizeof(int), stream);

    hist_kernel<<<(N_EDGES + 255) / 256, 256, 0, stream>>>(ei, counts);
    scan_kernel<<<1, 1024, 0, stream>>>(counts);
    copycur_kernel<<<(N_NODES + 255) / 256, 256, 0, stream>>>(counts, cursor);
    scatter_kernel<<<(N_EDGES + 255) / 256, 256, 0, stream>>>(ei, cursor, es);
    main_kernel<<<N_NODES / NB, 256, 0, stream>>>(x, ei, ea, W1, b1, W2, b2,
                                                  counts, cursor, es, out);
    finalize_kernel<<<(N_NODES * DIM_OUT + 255) / 256, 256, 0, stream>>>(x, root, bias, out);
}

// Round 3
// 604.635 us; speedup vs baseline: 2.4253x; 2.4253x over previous
//
#include <hip/hip_runtime.h>

// Problem constants (match reference)
#define N_NODES 10000
#define N_EDGES 160000
#define DIM_IN 32
#define DIM_OUT 64
#define DIM_HID 128
#define BOND 13
#define NB 4  // source nodes per workgroup in main kernel (one per wave)

typedef _Float16 half2_t __attribute__((ext_vector_type(2)));
typedef unsigned int uint;

static __device__ __forceinline__ float fdot2u(uint a, uint b, float c) {
#if __has_builtin(__builtin_amdgcn_fdot2)
    return __builtin_amdgcn_fdot2(__builtin_bit_cast(half2_t, a),
                                  __builtin_bit_cast(half2_t, b), c, false);
#else
    half2_t ha = __builtin_bit_cast(half2_t, a);
    half2_t hb = __builtin_bit_cast(half2_t, b);
    return c + (float)ha.x * (float)hb.x + (float)ha.y * (float)hb.y;
#endif
}

static __device__ __forceinline__ uint packh2(float a, float b) {
    half2_t h;
    h.x = (_Float16)a; h.y = (_Float16)b;
    return __builtin_bit_cast(uint, h);
}

// ---- CSR build: histogram of src ----
__global__ void hist_kernel(const int* __restrict__ ei, int* __restrict__ counts) {
    int e = blockIdx.x * 256 + threadIdx.x;
    if (e < N_EDGES) atomicAdd(&counts[ei[e]], 1);
}

// ---- single-block exclusive scan in place (counts -> offsets) ----
__global__ void scan_kernel(int* __restrict__ counts) {
    __shared__ int s[1024];
    const int t = threadIdx.x;
    const int base = t * 10;  // 1024*10 >= 10000
    int loc[10];
    int sum = 0;
#pragma unroll
    for (int u = 0; u < 10; ++u) {
        int idx = base + u;
        int v = (idx < N_NODES) ? counts[idx] : 0;
        loc[u] = v; sum += v;
    }
    s[t] = sum;
    __syncthreads();
    for (int off = 1; off < 1024; off <<= 1) {
        int add = (t >= off) ? s[t - off] : 0;
        __syncthreads();
        s[t] += add;
        __syncthreads();
    }
    int run = s[t] - sum;
#pragma unroll
    for (int u = 0; u < 10; ++u) {
        int idx = base + u;
        if (idx < N_NODES) counts[idx] = run;
        run += loc[u];
    }
}

__global__ void copycur_kernel(const int* __restrict__ off, int* __restrict__ cur) {
    int i = blockIdx.x * 256 + threadIdx.x;
    if (i < N_NODES) cur[i] = off[i];
}

// ---- scatter edge ids into CSR order (cursor ends up = offsets[n+1]) ----
__global__ void scatter_kernel(const int* __restrict__ ei, int* __restrict__ cur,
                               int* __restrict__ es) {
    int e = blockIdx.x * 256 + threadIdx.x;
    if (e < N_EDGES) {
        int pos = atomicAdd(&cur[ei[e]], 1);
        es[pos] = e;
    }
}

// ---- W2 f32 [k][i*64+o] -> f16 transposed [i*64+o][k] ----
__global__ void prep_w2(const float* __restrict__ W2, unsigned short* __restrict__ W2t) {
    int idx = blockIdx.x * 256 + threadIdx.x;  // 262144 total
    int k = idx >> 11;        // 0..127
    int c = idx & 2047;       // i*64+o
    _Float16 h = (_Float16)W2[idx];
    W2t[c * DIM_HID + k] = __builtin_bit_cast(unsigned short, h);
}

// ---- main: cooperative P build -> per-wave register P -> wave-autonomous edges ----
__global__ __launch_bounds__(256) void main_kernel(
    const float* __restrict__ x, const int* __restrict__ ei,
    const float* __restrict__ ea, const float* __restrict__ W1,
    const float* __restrict__ b1, const unsigned short* __restrict__ W2t,
    const float* __restrict__ b2, const int* __restrict__ offsets,
    const int* __restrict__ cursor, const int* __restrict__ es,
    float* __restrict__ agg)
{
    __shared__ uint  Ph[NB][DIM_HID / 2][DIM_OUT];  // f16x2 pairs, 64 KiB
    __shared__ float W1s[BOND][DIM_HID];            // 6656 B
    __shared__ float b1s[DIM_HID];
    __shared__ float xs_t[DIM_IN][NB];              // xs_t[i][node]
    __shared__ uint  hscr[NB][DIM_OUT];             // per-wave h scratch (f16x2)

    const int t  = threadIdx.x;
    const int o  = t & 63;
    const int w  = t >> 6;    // wave id 0..3 == node slot
    const int n0 = blockIdx.x * NB;

    // stage x, W1, b1
    if (t < DIM_IN * NB) {
        int i = t >> 2, j = t & 3;
        xs_t[i][j] = x[(n0 + j) * DIM_IN + i];
    }
    for (int u = t; u < BOND * DIM_HID; u += 256) ((float*)W1s)[u] = W1[u];
    if (t < DIM_HID) b1s[t] = b1[t];
    __syncthreads();

    // ---- P build: thread (w,o) covers k in [w*32, w*32+32), 8 k at a time ----
#pragma unroll
    for (int s = 0; s < 4; ++s) {
        const int kbase = w * 32 + s * 8;
        float acc[NB][8];
#pragma unroll
        for (int j = 0; j < NB; ++j)
#pragma unroll
            for (int q = 0; q < 8; ++q) acc[j][q] = 0.f;
        const uint4* w2p = (const uint4*)(W2t + kbase);  // + (i*64+o)*128 halfs
#pragma unroll
        for (int i = 0; i < DIM_IN; ++i) {
            uint4 wv = w2p[(i * 64 + o) * (DIM_HID / 8)];  // uint4 index: halfs/8
            float f[8];
            {
                half2_t h0 = __builtin_bit_cast(half2_t, wv.x);
                half2_t h1 = __builtin_bit_cast(half2_t, wv.y);
                half2_t h2 = __builtin_bit_cast(half2_t, wv.z);
                half2_t h3 = __builtin_bit_cast(half2_t, wv.w);
                f[0] = (float)h0.x; f[1] = (float)h0.y;
                f[2] = (float)h1.x; f[3] = (float)h1.y;
                f[4] = (float)h2.x; f[5] = (float)h2.y;
                f[6] = (float)h3.x; f[7] = (float)h3.y;
            }
            float4 xv = *(const float4*)&xs_t[i][0];
#pragma unroll
            for (int q = 0; q < 8; ++q) {
                acc[0][q] += xv.x * f[q];
                acc[1][q] += xv.y * f[q];
                acc[2][q] += xv.z * f[q];
                acc[3][q] += xv.w * f[q];
            }
        }
#pragma unroll
        for (int j = 0; j < NB; ++j)
#pragma unroll
            for (int q2 = 0; q2 < 4; ++q2)
                Ph[j][kbase / 2 + q2][o] = packh2(acc[j][2 * q2], acc[j][2 * q2 + 1]);
    }
    __syncthreads();

    // ---- transpose node w's P into this wave's registers ----
    uint preg[DIM_HID / 2];
#pragma unroll
    for (int kp = 0; kp < DIM_HID / 2; ++kp) preg[kp] = Ph[w][kp][o];

    // qreg = sum_i x[n,i] * b2[i*64+o]
    float qreg = 0.f;
#pragma unroll
    for (int i = 0; i < DIM_IN; ++i) qreg += xs_t[i][w] * b2[i * DIM_OUT + o];

    // ---- wave-autonomous edge loop (no block barriers) ----
    const int n = n0 + w;
    const int start = offsets[n];
    const int end   = cursor[n];  // == offsets[n+1]
    const float2* w1v = (const float2*)W1s;  // [jj][pair l]
    uint4* h4 = (uint4*)hscr[w];

    for (int p = start; p < end; ++p) {
        const int e   = __builtin_amdgcn_readfirstlane(es[p]);
        const int dst = __builtin_amdgcn_readfirstlane(ei[N_EDGES + e]);
        // h[2o], h[2o+1] = relu(ea[e] @ W1 + b1)
        float a0 = b1s[2 * o], a1 = b1s[2 * o + 1];
        const float* eap = ea + (long)e * BOND;
#pragma unroll
        for (int jj = 0; jj < BOND; ++jj) {
            float ej = eap[jj];
            float2 wv = w1v[jj * (DIM_HID / 2) + o];
            a0 += ej * wv.x; a1 += ej * wv.y;
        }
        a0 = a0 > 0.f ? a0 : 0.f;
        a1 = a1 > 0.f ? a1 : 0.f;
        __builtin_amdgcn_wave_barrier();
        hscr[w][o] = packh2(a0, a1);
        __builtin_amdgcn_wave_barrier();
        // msg[o] = qreg + sum_k h[k] * P[k][o]
        float acc = qreg;
#pragma unroll
        for (int m = 0; m < 16; ++m) {
            uint4 hv = h4[m];
            acc = fdot2u(hv.x, preg[4 * m + 0], acc);
            acc = fdot2u(hv.y, preg[4 * m + 1], acc);
            acc = fdot2u(hv.z, preg[4 * m + 2], acc);
            acc = fdot2u(hv.w, preg[4 * m + 3], acc);
        }
        atomicAdd(&agg[(long)dst * DIM_OUT + o], acc);
    }
}

// ---- finalize: out = relu(agg + x@root + bias), in place on d_out ----
__global__ void finalize_kernel(const float* __restrict__ x,
                                const float* __restrict__ root,
                                const float* __restrict__ bias,
                                float* __restrict__ out) {
    int idx = blockIdx.x * 256 + threadIdx.x;
    if (idx >= N_NODES * DIM_OUT) return;
    int n = idx >> 6, o = idx & 63;
    float r = bias[o];
    const float* xn = x + n * DIM_IN;
#pragma unroll
    for (int i = 0; i < DIM_IN; ++i) r += xn[i] * root[i * DIM_OUT + o];
    float v = out[idx] + r;
    out[idx] = v > 0.f ? v : 0.f;
}

extern "C" void kernel_launch(void* const* d_in, const int* in_sizes, int n_in,
                              void* d_out, int out_size, void* d_ws, size_t ws_size,
                              hipStream_t stream) {
    const float* x    = (const float*)d_in[0];
    const int*   ei   = (const int*)d_in[1];   // [2, E]: row 0 = src, row 1 = dst
    const float* ea   = (const float*)d_in[2];
    const float* W1   = (const float*)d_in[3];
    const float* b1   = (const float*)d_in[4];
    const float* W2   = (const float*)d_in[5];
    const float* b2   = (const float*)d_in[6];
    const float* root = (const float*)d_in[7];
    const float* bias = (const float*)d_in[8];
    float* out = (float*)d_out;

    // Workspace layout (~1.2 MB; ws re-poisoned each call so rebuild everything)
    char* ws = (char*)d_ws;
    int* counts = (int*)(ws);                         // 40000 B (-> offsets)
    int* cursor = (int*)(ws + 40064);                 // 40000 B (-> offsets[n+1])
    int* es     = (int*)(ws + 80128);                 // 640000 B
    unsigned short* W2t = (unsigned short*)(ws + 720384);  // 524288 B, 16B-aligned

    hipMemsetAsync(d_out, 0, (size_t)N_NODES * DIM_OUT * sizeof(float), stream);
    hipMemsetAsync(counts, 0, N_NODES * sizeof(int), stream);

    prep_w2<<<(DIM_HID * DIM_IN * DIM_OUT) / 256, 256, 0, stream>>>(W2, W2t);
    hist_kernel<<<(N_EDGES + 255) / 256, 256, 0, stream>>>(ei, counts);
    scan_kernel<<<1, 1024, 0, stream>>>(counts);
    copycur_kernel<<<(N_NODES + 255) / 256, 256, 0, stream>>>(counts, cursor);
    scatter_kernel<<<(N_EDGES + 255) / 256, 256, 0, stream>>>(ei, cursor, es);
    main_kernel<<<N_NODES / NB, 256, 0, stream>>>(x, ei, ea, W1, b1, W2t, b2,
                                                  counts, cursor, es, out);
    finalize_kernel<<<(N_NODES * DIM_OUT + 255) / 256, 256, 0, stream>>>(x, root, bias, out);
}

// Round 4
// 439.648 us; speedup vs baseline: 3.3355x; 1.3753x over previous
//
#include <hip/hip_runtime.h>

// Problem constants (match reference)
#define N_NODES 10000
#define N_EDGES 160000
#define DIM_IN 32
#define DIM_OUT 64
#define DIM_HID 128
#define BOND 13
#define NB 4  // source nodes per workgroup (one per wave)

typedef _Float16 half2_t __attribute__((ext_vector_type(2)));
typedef unsigned int uint;

static __device__ __forceinline__ float fdot2u(uint a, uint b, float c) {
#if __has_builtin(__builtin_amdgcn_fdot2)
    return __builtin_amdgcn_fdot2(__builtin_bit_cast(half2_t, a),
                                  __builtin_bit_cast(half2_t, b), c, false);
#else
    half2_t ha = __builtin_bit_cast(half2_t, a);
    half2_t hb = __builtin_bit_cast(half2_t, b);
    return c + (float)ha.x * (float)hb.x + (float)ha.y * (float)hb.y;
#endif
}

static __device__ __forceinline__ uint packh2(float a, float b) {
    half2_t h;
    h.x = (_Float16)a; h.y = (_Float16)b;
    return __builtin_bit_cast(uint, h);
}

// ---- prep: W2 -> f16x2 i-paired layout W2p[(ip*64+o)*128 + k]; zero agg; zero counts
__global__ void prep_kernel(const float* __restrict__ W2, uint* __restrict__ W2p,
                            float* __restrict__ agg, int* __restrict__ counts) {
    int idx = blockIdx.x * 256 + threadIdx.x;  // grid covers 640000
    if (idx < 16 * 64 * DIM_HID) {             // 131072
        int ip = idx >> 13;
        int o  = (idx >> 7) & 63;
        int k  = idx & 127;
        float lo = W2[k * 2048 + (2 * ip) * 64 + o];
        float hi = W2[k * 2048 + (2 * ip + 1) * 64 + o];
        W2p[idx] = packh2(lo, hi);
    }
    if (idx < N_NODES * DIM_OUT) agg[idx] = 0.f;
    if (idx < N_NODES) counts[idx] = 0;
}

// ---- CSR build: histogram of src ----
__global__ void hist_kernel(const int* __restrict__ ei, int* __restrict__ counts) {
    int e = blockIdx.x * 256 + threadIdx.x;
    if (e < N_EDGES) atomicAdd(&counts[ei[e]], 1);
}

// ---- single-block exclusive scan in place; also writes cursor copy ----
__global__ void scan_kernel(int* __restrict__ counts, int* __restrict__ cursor) {
    __shared__ int s[1024];
    const int t = threadIdx.x;
    const int base = t * 10;  // 1024*10 >= 10000
    int loc[10];
    int sum = 0;
#pragma unroll
    for (int u = 0; u < 10; ++u) {
        int idx = base + u;
        int v = (idx < N_NODES) ? counts[idx] : 0;
        loc[u] = v; sum += v;
    }
    s[t] = sum;
    __syncthreads();
    for (int off = 1; off < 1024; off <<= 1) {
        int add = (t >= off) ? s[t - off] : 0;
        __syncthreads();
        s[t] += add;
        __syncthreads();
    }
    int run = s[t] - sum;
#pragma unroll
    for (int u = 0; u < 10; ++u) {
        int idx = base + u;
        if (idx < N_NODES) { counts[idx] = run; cursor[idx] = run; }
        run += loc[u];
    }
}

// ---- scatter edge ids into CSR order (cursor ends up = offsets[n+1]) ----
__global__ void scatter_kernel(const int* __restrict__ ei, int* __restrict__ cur,
                               int* __restrict__ es) {
    int e = blockIdx.x * 256 + threadIdx.x;
    if (e < N_EDGES) {
        int pos = atomicAdd(&cur[ei[e]], 1);
        es[pos] = e;
    }
}

// per-wave edge scratch, overlaid on this wave's 16 KB Ph slot after preg load
struct EScr {
    int   eids[64];
    int   dsts[64];
    float eas[8][16];   // 16B-aligned rows
    uint  hbuf[8][64];  // offset 1536: 16B aligned for uint4 reads
};

// ---- main: cooperative P build -> register P -> tiled, prefetched edge phase ----
__global__ __launch_bounds__(256) void main_kernel(
    const float* __restrict__ x, const int* __restrict__ ei,
    const float* __restrict__ ea, const float* __restrict__ W1,
    const float* __restrict__ b1, const uint* __restrict__ W2p,
    const float* __restrict__ b2, const int* __restrict__ offsets,
    const int* __restrict__ cursor, const int* __restrict__ es,
    float* __restrict__ agg)
{
    __shared__ uint  Ph[NB][DIM_HID / 2][DIM_OUT];  // 64 KiB, reused as EScr later
    __shared__ float xs_t[DIM_IN][NB];
    __shared__ uint  xsp[DIM_IN / 2][NB];           // f16x2 (x[2ip],x[2ip+1])

    const int t  = threadIdx.x;
    const int o  = t & 63;
    const int w  = t >> 6;
    const int n0 = blockIdx.x * NB;

    if (t < DIM_IN * NB) {
        int i = t >> 2, j = t & 3;
        xs_t[i][j] = x[(n0 + j) * DIM_IN + i];
    }
    __syncthreads();
    if (t < (DIM_IN / 2) * NB) {
        int ip = t >> 2, j = t & 3;
        xsp[ip][j] = packh2(xs_t[2 * ip][j], xs_t[2 * ip + 1][j]);
    }
    __syncthreads();

    // ---- P build: thread (w,o) covers k in [w*32,w*32+32), pure fdot2 ----
#pragma unroll
    for (int s = 0; s < 4; ++s) {
        const int kbase = w * 32 + s * 8;
        float acc[NB][8];
#pragma unroll
        for (int j = 0; j < NB; ++j)
#pragma unroll
            for (int q = 0; q < 8; ++q) acc[j][q] = 0.f;
#pragma unroll
        for (int ip = 0; ip < 16; ++ip) {
            const uint4* p4 = (const uint4*)(W2p + (ip * 64 + o) * DIM_HID + kbase);
            uint4 wa = p4[0];  // k..k+3 (each uint = i-pair for one k)
            uint4 wb = p4[1];  // k+4..k+7
            uint xp0 = xsp[ip][0], xp1 = xsp[ip][1];
            uint xp2 = xsp[ip][2], xp3 = xsp[ip][3];
#define DO_NODE(j, xp) \
            acc[j][0] = fdot2u(xp, wa.x, acc[j][0]); \
            acc[j][1] = fdot2u(xp, wa.y, acc[j][1]); \
            acc[j][2] = fdot2u(xp, wa.z, acc[j][2]); \
            acc[j][3] = fdot2u(xp, wa.w, acc[j][3]); \
            acc[j][4] = fdot2u(xp, wb.x, acc[j][4]); \
            acc[j][5] = fdot2u(xp, wb.y, acc[j][5]); \
            acc[j][6] = fdot2u(xp, wb.z, acc[j][6]); \
            acc[j][7] = fdot2u(xp, wb.w, acc[j][7]);
            DO_NODE(0, xp0) DO_NODE(1, xp1) DO_NODE(2, xp2) DO_NODE(3, xp3)
#undef DO_NODE
        }
#pragma unroll
        for (int j = 0; j < NB; ++j)
#pragma unroll
            for (int q2 = 0; q2 < 4; ++q2)
                Ph[j][kbase / 2 + q2][o] = packh2(acc[j][2 * q2], acc[j][2 * q2 + 1]);
    }
    __syncthreads();

    // ---- node w's P into this wave's registers ----
    uint preg[DIM_HID / 2];
#pragma unroll
    for (int kp = 0; kp < DIM_HID / 2; ++kp) preg[kp] = Ph[w][kp][o];

    // qreg = sum_i x[n,i] * b2[i*64+o]
    float qreg = 0.f;
#pragma unroll
    for (int i = 0; i < DIM_IN; ++i) qreg += xs_t[i][w] * b2[i * DIM_OUT + o];

    // hoist W1 column pair + b1 pair for lane o
    float2 wcol[BOND];
#pragma unroll
    for (int q = 0; q < BOND; ++q)
        wcol[q] = *(const float2*)(W1 + q * DIM_HID + 2 * o);
    float2 bc = *(const float2*)(b1 + 2 * o);

    // ---- edge phase: wave-autonomous, tiled by 8 with ea prefetch ----
    EScr* S = (EScr*)&Ph[w][0][0];  // reuse own slot (only this wave touches it)
    const int n = n0 + w;
    const int start = offsets[n];
    const int deg   = cursor[n] - start;
    const int jj    = o & 15;
    const int prow  = o >> 4;  // 0..3

    for (int gbase = 0; gbase < deg; gbase += 64) {
        const int cnt = (deg - gbase < 64) ? (deg - gbase) : 64;
        __builtin_amdgcn_wave_barrier();
        if (o < cnt) {
            int e = es[start + gbase + o];
            S->eids[o] = e;
            S->dsts[o] = ei[N_EDGES + e];
        }
        __builtin_amdgcn_wave_barrier();
        const int ntiles = (cnt + 7) >> 3;
        float v0, v1;
        {   // fetch tile 0: lane covers (edge prow, col jj) and (edge prow+4, col jj)
            int pa = prow, pb = prow + 4;
            bool a0 = (jj < BOND) && (pa < cnt);
            bool a1 = (jj < BOND) && (pb < cnt);
            v0 = a0 ? ea[(long)S->eids[pa] * BOND + jj] : 0.f;
            v1 = a1 ? ea[(long)S->eids[pb] * BOND + jj] : 0.f;
        }
        for (int tb = 0; tb < ntiles; ++tb) {
            __builtin_amdgcn_wave_barrier();
            S->eas[prow][jj]     = v0;
            S->eas[prow + 4][jj] = v1;
            __builtin_amdgcn_wave_barrier();
            // h for all 8 tile edges (dead slots compute garbage, never used)
#pragma unroll
            for (int p = 0; p < 8; ++p) {
                const float4* e4 = (const float4*)S->eas[p];
                float4 ev0 = e4[0], ev1 = e4[1], ev2 = e4[2], ev3 = e4[3];
                float h0 = bc.x, h1 = bc.y;
                float eq[BOND] = {ev0.x, ev0.y, ev0.z, ev0.w,
                                  ev1.x, ev1.y, ev1.z, ev1.w,
                                  ev2.x, ev2.y, ev2.z, ev2.w, ev3.x};
#pragma unroll
                for (int q = 0; q < BOND; ++q) {
                    h0 += eq[q] * wcol[q].x;
                    h1 += eq[q] * wcol[q].y;
                }
                S->hbuf[p][o] = packh2(h0 > 0.f ? h0 : 0.f, h1 > 0.f ? h1 : 0.f);
            }
            // prefetch next tile's ea during this tile's dot
            if (tb + 1 < ntiles) {
                int pa = (tb + 1) * 8 + prow, pb = pa + 4;
                bool a0 = (jj < BOND) && (pa < cnt);
                bool a1 = (jj < BOND) && (pb < cnt);
                v0 = a0 ? ea[(long)S->eids[pa] * BOND + jj] : 0.f;
                v1 = a1 ? ea[(long)S->eids[pb] * BOND + jj] : 0.f;
            }
            __builtin_amdgcn_wave_barrier();
            const int tcnt = cnt - tb * 8;  // valid edges this tile (clamped by p<8)
#pragma unroll
            for (int p = 0; p < 8; ++p) {
                if (p < tcnt) {
                    const uint4* h4 = (const uint4*)S->hbuf[p];
                    float acc = qreg;
#pragma unroll
                    for (int m = 0; m < 16; ++m) {
                        uint4 hv = h4[m];
                        acc = fdot2u(hv.x, preg[4 * m + 0], acc);
                        acc = fdot2u(hv.y, preg[4 * m + 1], acc);
                        acc = fdot2u(hv.z, preg[4 * m + 2], acc);
                        acc = fdot2u(hv.w, preg[4 * m + 3], acc);
                    }
                    int dst = __builtin_amdgcn_readfirstlane(S->dsts[tb * 8 + p]);
                    atomicAdd(&agg[(long)dst * DIM_OUT + o], acc);
                }
            }
        }
    }
}

// ---- finalize: out = relu(agg + x@root + bias), in place on d_out ----
__global__ void finalize_kernel(const float* __restrict__ x,
                                const float* __restrict__ root,
                                const float* __restrict__ bias,
                                float* __restrict__ out) {
    int idx = blockIdx.x * 256 + threadIdx.x;
    if (idx >= N_NODES * DIM_OUT) return;
    int n = idx >> 6, o = idx & 63;
    float r = bias[o];
    const float* xn = x + n * DIM_IN;
#pragma unroll
    for (int i = 0; i < DIM_IN; ++i) r += xn[i] * root[i * DIM_OUT + o];
    float v = out[idx] + r;
    out[idx] = v > 0.f ? v : 0.f;
}

extern "C" void kernel_launch(void* const* d_in, const int* in_sizes, int n_in,
                              void* d_out, int out_size, void* d_ws, size_t ws_size,
                              hipStream_t stream) {
    const float* x    = (const float*)d_in[0];
    const int*   ei   = (const int*)d_in[1];   // [2, E]: row 0 = src, row 1 = dst
    const float* ea   = (const float*)d_in[2];
    const float* W1   = (const float*)d_in[3];
    const float* b1   = (const float*)d_in[4];
    const float* W2   = (const float*)d_in[5];
    const float* b2   = (const float*)d_in[6];
    const float* root = (const float*)d_in[7];
    const float* bias = (const float*)d_in[8];
    float* out = (float*)d_out;

    // Workspace (~1.22 MB; ws re-poisoned each call so rebuild everything)
    char* ws = (char*)d_ws;
    int*  counts = (int*)(ws);                    // 40000 B (-> offsets)
    int*  cursor = (int*)(ws + 40064);            // 40000 B (-> offsets[n+1])
    int*  es     = (int*)(ws + 80128);            // 640000 B
    uint* W2p    = (uint*)(ws + 720384);          // 524288 B, 16B-aligned

    prep_kernel<<<2500, 256, 0, stream>>>(W2, W2p, out, counts);
    hist_kernel<<<(N_EDGES + 255) / 256, 256, 0, stream>>>(ei, counts);
    scan_kernel<<<1, 1024, 0, stream>>>(counts, cursor);
    scatter_kernel<<<(N_EDGES + 255) / 256, 256, 0, stream>>>(ei, cursor, es);
    main_kernel<<<N_NODES / NB, 256, 0, stream>>>(x, ei, ea, W1, b1, W2p, b2,
                                                  counts, cursor, es, out);
    finalize_kernel<<<(N_NODES * DIM_OUT + 255) / 256, 256, 0, stream>>>(x, root, bias, out);
}